// Round 5
// baseline (1979.684 us; speedup 1.0000x reference)
//
#include <hip/hip_runtime.h>
#include <math.h>

// BarrierNet fused kernel, fp32 (round 5 = round 4 resubmitted verbatim;
// round 4 never ran — GPU acquisition timeout).
// ROUND-3 BUG FIX: reference feeds RAW x into the network (h1 = relu(x@W1.T+b1));
// only the CBF physics uses x0 = x*STD+MEAN. Round-3 kernel fed x0 into W1 ->
// absmax 254 via the lam=(Gu-h)/gg amplification path. xl now holds raw x;
// epilogue un-normalizes locally (and runs in fp64: 64 lanes/block, free,
// minimizes divergence on ill-conditioned small-gg rows).
// Structure per block (512 threads = 8 waves, 64 rows):
//   phase0: load raw x -> LDS
//   phase1: h1 = relu(x @ W1^T + b1) -> LDS [k][row]  (128 KiB)
//   phase2: per-wave 32-col GEMM slice over concat(W21,W22), wave-uniform
//           scalar weight loads from transposed Wt[k][c];
//           fused bias+relu+partial layer-3 dots -> LDS reduce
//   epilogue: wave 0 computes CBF-QP closed form (fp64), stores float2.

#define NBATCH 262144
#define MT 64
#define NTHREADS 512

__global__ void transpose_w_kernel(const float* __restrict__ W21,
                                   const float* __restrict__ W22,
                                   float* __restrict__ Wt) {
    int idx = blockIdx.x * blockDim.x + threadIdx.x;  // 0..131071
    if (idx >= 512 * 256) return;
    int k = idx >> 8;    // 0..511
    int c = idx & 255;   // 0..255
    float v = (c < 128) ? W21[c * 512 + k] : W22[(c - 128) * 512 + k];
    Wt[idx] = v;         // Wt[k][c]
}

__global__ __launch_bounds__(NTHREADS, 2)
void barriernet_kernel(const float* __restrict__ x,
                       const float* __restrict__ W1,  const float* __restrict__ b1,
                       const float* __restrict__ b21, const float* __restrict__ b22,
                       const float* __restrict__ W31, const float* __restrict__ b31,
                       const float* __restrict__ W32, const float* __restrict__ b32,
                       const float* __restrict__ Wt,
                       float* __restrict__ out) {
    __shared__ float h1s[512 * MT];      // [k][row], 128 KiB
    __shared__ float xl[MT][4];          // RAW x per row (network input!)
    __shared__ float red[8][MT][2];      // layer-3 partials per wave

    const int t    = threadIdx.x;
    const int lane = t & 63;
    const int wv   = __builtin_amdgcn_readfirstlane(t >> 6);  // 0..7, wave-uniform
    const int row0 = blockIdx.x * MT;

    // ---- phase 0: load RAW x (coalesced: waves 0-3, one float per thread) ----
    if (t < 256) {
        const int r = t >> 2;            // row 0..63
        const int c = t & 3;             // component
        xl[r][c] = x[(size_t)(row0 + r) * 4 + c];
    }
    __syncthreads();

    // ---- phase 1: h1 = relu(x @ W1^T + b1) into LDS [k][row] ----
    {
        const int row = lane;
        const float a0 = xl[row][0], a1 = xl[row][1], a2 = xl[row][2], a3 = xl[row][3];
        #pragma unroll 4
        for (int i = 0; i < 64; ++i) {
            const int k = wv * 64 + i;       // wave-uniform
            const float* w1k = W1 + k * 4;   // -> scalar loads
            float v = b1[k];
            v = fmaf(a0, w1k[0], v);
            v = fmaf(a1, w1k[1], v);
            v = fmaf(a2, w1k[2], v);
            v = fmaf(a3, w1k[3], v);
            h1s[k * MT + row] = fmaxf(v, 0.f);
        }
    }
    __syncthreads();

    // ---- phase 2: GEMM slice, cols [wv*32, wv*32+32) of concat(h21,h22) ----
    // Per k-step: 1 ds_read_b32 (conflict-free) + wave-uniform s_load weight
    // slice + 32 v_fmac_f32. unroll 4 = 4 independent staging streams (ILP is
    // the latency hider at 2 waves/SIMD).
    const int cbase = wv * 32;           // wave-uniform
    float acc[32];
    #pragma unroll
    for (int j = 0; j < 32; ++j) acc[j] = 0.f;

    #pragma unroll 4
    for (int k = 0; k < 512; ++k) {
        const float a = h1s[k * MT + lane];
        const float* wk = Wt + k * 256 + cbase;      // wave-uniform -> s_load
        #pragma unroll
        for (int j = 0; j < 32; ++j) acc[j] = fmaf(a, wk[j], acc[j]);
    }

    // ---- bias + relu + partial dots with W31/W32 (layer 3) ----
    {
        const bool isA  = (wv < 4);
        const int  coff = isA ? cbase : (cbase - 128);   // col within its matrix
        const float* bb = isA ? b21 : b22;
        const float* W3 = isA ? W31 : W32;               // (2,128) row-major
        float q0 = 0.f, q1 = 0.f;
        #pragma unroll
        for (int j = 0; j < 32; ++j) {
            float hv = fmaxf(acc[j] + bb[coff + j], 0.f);
            q0 = fmaf(hv, W3[coff + j], q0);
            q1 = fmaf(hv, W3[128 + coff + j], q1);
        }
        red[wv][lane][0] = q0;
        red[wv][lane][1] = q1;
    }
    __syncthreads();

    // ---- epilogue: CBF-QP closed form (wave 0, one lane per row, fp64) ----
    if (t < MT) {
        const int r = t;
        float x31_0f = b31[0], x31_1f = b31[1];
        float z0f = b32[0], z1f = b32[1];
        #pragma unroll
        for (int w = 0; w < 4; ++w) { x31_0f += red[w][r][0]; x31_1f += red[w][r][1]; }
        #pragma unroll
        for (int w = 4; w < 8; ++w) { z0f += red[w][r][0]; z1f += red[w][r][1]; }

        const double s0 = 4.0 / (1.0 + exp(-(double)z0f));
        const double s1 = 4.0 / (1.0 + exp(-(double)z1f));

        // un-normalize raw x for the physics: STD={10,10,1,2}, MEAN={50,20,0,5}
        const double px = (double)xl[r][0] * 10.0 + 50.0;
        const double py = (double)xl[r][1] * 10.0 + 20.0;
        const double th = (double)xl[r][2];
        const double v  = (double)xl[r][3] * 2.0 + 5.0;

        const double st = sin(th), ct = cos(th);
        const double dx = px - 40.0, dy = py - 15.0;
        const double barrier     = dx * dx + dy * dy - 36.0;
        const double barrier_dot = 2.0 * dx * v * ct + 2.0 * dy * v * st;
        const double Lf2b        = 2.0 * v * v;
        const double LgLfbu1     = -2.0 * dx * v * st + 2.0 * dy * v * ct;
        const double LgLfbu2     = 2.0 * dx * ct + 2.0 * dy * st;
        const double G0 = -LgLfbu1, G1 = -LgLfbu2;
        const double h  = Lf2b + (s0 + s1) * barrier_dot + s0 * s1 * barrier;
        const double u0 = -(double)x31_0f, u1 = -(double)x31_1f;
        const double Gu = G0 * u0 + G1 * u1;
        const double gg = fmax(G0 * G0 + G1 * G1, 1e-12);
        const double lam = fmax(0.0, (Gu - h) / gg);
        float2 o;
        o.x = (float)(u0 - lam * G0);
        o.y = (float)(u1 - lam * G1);
        reinterpret_cast<float2*>(out)[row0 + r] = o;
    }
}

extern "C" void kernel_launch(void* const* d_in, const int* in_sizes, int n_in,
                              void* d_out, int out_size, void* d_ws, size_t ws_size,
                              hipStream_t stream) {
    const float* x   = (const float*)d_in[0];
    const float* W1  = (const float*)d_in[1];
    const float* b1  = (const float*)d_in[2];
    const float* W21 = (const float*)d_in[3];
    const float* b21 = (const float*)d_in[4];
    const float* W22 = (const float*)d_in[5];
    const float* b22 = (const float*)d_in[6];
    const float* W31 = (const float*)d_in[7];
    const float* b31 = (const float*)d_in[8];
    const float* W32 = (const float*)d_in[9];
    const float* b32 = (const float*)d_in[10];
    // d_in[11] = sgn, unused by the reference forward pass.

    float* Wt  = (float*)d_ws;           // 512*256*4 = 512 KiB, rebuilt every call
    float* out = (float*)d_out;

    transpose_w_kernel<<<dim3(512), dim3(256), 0, stream>>>(W21, W22, Wt);
    barriernet_kernel<<<dim3(NBATCH / MT), dim3(NTHREADS), 0, stream>>>(
        x, W1, b1, b21, b22, W31, b31, W32, b32, Wt, out);
}

// Round 10
// 976.743 us; speedup vs baseline: 2.0268x; 2.0268x over previous
//
#include <hip/hip_runtime.h>
#include <math.h>

// BarrierNet fused kernel, fp32, round 10 = round 6 resubmitted verbatim
// (rounds 6-9 never ran: GPU acquisition timeouts).
// Round-5 counters: dur 2016us, VALUBusy 24%, Occupancy 22% -> ~590 cyc/k-step
// vs 64-cyc VALU floor. Cause: per-k-step ds_read(h1s)+weight-load mix exposes
// SMEM latency (OOO lgkmcnt -> full drains), 2 waves/SIMD can't hide it.
// Fix: NO LDS in hot loop. Activations recomputed per-wave into registers
// (4 FMA + relu each from per-lane x + uniform W1), weights stay a wave-uniform
// s_load stream, steady loop = pure v_fmac. LDS only for the 4 KiB layer-3
// reduce -> occupancy 4 waves/SIMD (VGPR<=128), one barrier per block.
//   block = 512 thr (8 waves), 64 rows (lane=row), wave owns 32 cols of
//   concat(h21,h22); 16 chunks x 32 k.

#define NBATCH 262144
#define MT 64
#define NTHREADS 512
#define CHUNK 32
#define NCHUNK 16   // 512 / CHUNK

__global__ void transpose_w_kernel(const float* __restrict__ W21,
                                   const float* __restrict__ W22,
                                   float* __restrict__ Wt) {
    int idx = blockIdx.x * blockDim.x + threadIdx.x;  // 0..131071
    if (idx >= 512 * 256) return;
    int k = idx >> 8;    // 0..511
    int c = idx & 255;   // 0..255
    float v = (c < 128) ? W21[c * 512 + k] : W22[(c - 128) * 512 + k];
    Wt[idx] = v;         // Wt[k][c]
}

__global__ __launch_bounds__(NTHREADS, 4)
void barriernet_kernel(const float* __restrict__ x,
                       const float* __restrict__ W1,  const float* __restrict__ b1,
                       const float* __restrict__ b21, const float* __restrict__ b22,
                       const float* __restrict__ W31, const float* __restrict__ b31,
                       const float* __restrict__ W32, const float* __restrict__ b32,
                       const float* __restrict__ Wt,
                       float* __restrict__ out) {
    __shared__ float red[8][MT][2];      // layer-3 partials per wave (4 KiB)

    const int t    = threadIdx.x;
    const int lane = t & 63;             // = row within block
    const int wv   = __builtin_amdgcn_readfirstlane(t >> 6);  // 0..7 wave-uniform
    const int row0 = blockIdx.x * MT;

    // ---- per-lane raw x (row = lane), one coalesced 16B load ----
    const float4 xi = reinterpret_cast<const float4*>(x)[row0 + lane];
    const float a0 = xi.x, a1 = xi.y, a2 = xi.z, a3 = xi.w;

    // ---- fused recompute-h1 + GEMM over 16 chunks of 32 k ----
    const int cbase = wv * 32;           // wave-uniform col base
    float acc[32];
    #pragma unroll
    for (int j = 0; j < 32; ++j) acc[j] = 0.f;

    for (int c = 0; c < NCHUNK; ++c) {   // real loop: keep body in I-cache
        float act[32];
        // recompute activations for this chunk (uniform W1/b1 -> s_load)
        #pragma unroll
        for (int kk = 0; kk < CHUNK; ++kk) {
            const int k = c * CHUNK + kk;
            const float* w1k = W1 + k * 4;
            float v = b1[k];
            v = fmaf(a0, w1k[0], v);
            v = fmaf(a1, w1k[1], v);
            v = fmaf(a2, w1k[2], v);
            v = fmaf(a3, w1k[3], v);
            act[kk] = fmaxf(v, 0.f);
        }
        // pure-FMA GEMM: uniform weight stream, register activations
        #pragma unroll
        for (int kk = 0; kk < CHUNK; ++kk) {
            const float* wk = Wt + (c * CHUNK + kk) * 256 + cbase;  // uniform
            #pragma unroll
            for (int j = 0; j < 32; ++j) acc[j] = fmaf(act[kk], wk[j], acc[j]);
        }
    }

    // ---- bias + relu + partial dots with W31/W32 (layer 3) ----
    {
        const bool isA  = (wv < 4);
        const int  coff = isA ? cbase : (cbase - 128);   // col within its matrix
        const float* bb = isA ? b21 : b22;
        const float* W3 = isA ? W31 : W32;               // (2,128) row-major
        float q0 = 0.f, q1 = 0.f;
        #pragma unroll
        for (int j = 0; j < 32; ++j) {
            float hv = fmaxf(acc[j] + bb[coff + j], 0.f);
            q0 = fmaf(hv, W3[coff + j], q0);
            q1 = fmaf(hv, W3[128 + coff + j], q1);
        }
        red[wv][lane][0] = q0;
        red[wv][lane][1] = q1;
    }
    __syncthreads();

    // ---- epilogue: CBF-QP closed form (wave 0, one lane per row, fp64) ----
    if (t < MT) {
        const int r = t;                 // lane==row, wave 0 -> own x regs valid
        float x31_0f = b31[0], x31_1f = b31[1];
        float z0f = b32[0], z1f = b32[1];
        #pragma unroll
        for (int w = 0; w < 4; ++w) { x31_0f += red[w][r][0]; x31_1f += red[w][r][1]; }
        #pragma unroll
        for (int w = 4; w < 8; ++w) { z0f += red[w][r][0]; z1f += red[w][r][1]; }

        const double s0 = 4.0 / (1.0 + exp(-(double)z0f));
        const double s1 = 4.0 / (1.0 + exp(-(double)z1f));

        // un-normalize raw x for the physics: STD={10,10,1,2}, MEAN={50,20,0,5}
        const double px = (double)a0 * 10.0 + 50.0;
        const double py = (double)a1 * 10.0 + 20.0;
        const double th = (double)a2;
        const double v  = (double)a3 * 2.0 + 5.0;

        const double st = sin(th), ct = cos(th);
        const double dx = px - 40.0, dy = py - 15.0;
        const double barrier     = dx * dx + dy * dy - 36.0;
        const double barrier_dot = 2.0 * dx * v * ct + 2.0 * dy * v * st;
        const double Lf2b        = 2.0 * v * v;
        const double LgLfbu1     = -2.0 * dx * v * st + 2.0 * dy * v * ct;
        const double LgLfbu2     = 2.0 * dx * ct + 2.0 * dy * st;
        const double G0 = -LgLfbu1, G1 = -LgLfbu2;
        const double h  = Lf2b + (s0 + s1) * barrier_dot + s0 * s1 * barrier;
        const double u0 = -(double)x31_0f, u1 = -(double)x31_1f;
        const double Gu = G0 * u0 + G1 * u1;
        const double gg = fmax(G0 * G0 + G1 * G1, 1e-12);
        const double lam = fmax(0.0, (Gu - h) / gg);
        float2 o;
        o.x = (float)(u0 - lam * G0);
        o.y = (float)(u1 - lam * G1);
        reinterpret_cast<float2*>(out)[row0 + r] = o;
    }
}

extern "C" void kernel_launch(void* const* d_in, const int* in_sizes, int n_in,
                              void* d_out, int out_size, void* d_ws, size_t ws_size,
                              hipStream_t stream) {
    const float* x   = (const float*)d_in[0];
    const float* W1  = (const float*)d_in[1];
    const float* b1  = (const float*)d_in[2];
    const float* W21 = (const float*)d_in[3];
    const float* b21 = (const float*)d_in[4];
    const float* W22 = (const float*)d_in[5];
    const float* b22 = (const float*)d_in[6];
    const float* W31 = (const float*)d_in[7];
    const float* b31 = (const float*)d_in[8];
    const float* W32 = (const float*)d_in[9];
    const float* b32 = (const float*)d_in[10];
    // d_in[11] = sgn, unused by the reference forward pass.

    float* Wt  = (float*)d_ws;           // 512*256*4 = 512 KiB, rebuilt every call
    float* out = (float*)d_out;

    transpose_w_kernel<<<dim3(512), dim3(256), 0, stream>>>(W21, W22, Wt);
    barriernet_kernel<<<dim3(NBATCH / MT), dim3(NTHREADS), 0, stream>>>(
        x, W1, b1, b21, b22, W31, b31, W32, b32, Wt, out);
}